// Round 7
// baseline (3030.768 us; speedup 1.0000x reference)
//
#include <hip/hip_runtime.h>

#define S_LEN 128
#define T_LEN 64
#define BSZ   64
#define EMBD  256
#define HID_  512
#define DHID_ 1024
#define VOC_  32000
#define HSTR  1024

typedef float  f4_t  __attribute__((ext_vector_type(4)));
typedef float  f32x4 __attribute__((ext_vector_type(4)));
typedef short  s16x8 __attribute__((ext_vector_type(8)));
typedef __bf16 bf16x8 __attribute__((ext_vector_type(8)));
typedef unsigned short u16x4 __attribute__((ext_vector_type(4)));
typedef int    i32x2 __attribute__((ext_vector_type(2)));

// ---------------- workspace layout ----------------
// float offsets:
#define WS_CS   0ull                       // 131,072 fl (2 layers x (B,HSTR) fp32 c-state)
#define WS_BAR  (WS_CS + 131072ull)        // 32,768 ints (4 regions x 8192)
#define WS_BF   (WS_BAR + 32768ull)
// ushort offsets within bf16 region:
#define U_X0B   0ull                        // 2,097,152
#define U_HE0   (U_X0B  + 2097152ull)       // 8,388,608
#define U_HE1   (U_HE0  + 8388608ull)       // 8,388,608
#define U_HD0   (U_HE1  + 8388608ull)       // 4,194,304
#define U_HD1   (U_HD0  + 4194304ull)       // 4,194,304
#define U_HSB   (U_HD1  + 4194304ull)       // 131,072
#define U_E0W   (U_HSB  + 131072ull)        // 1,048,576
#define U_E1W   (U_E0W  + 1048576ull)       // 4,194,304
#define U_D0W   (U_E1W  + 4194304ull)       // 1,048,576
#define U_D1W   (U_D0W  + 1048576ull)       // 4,194,304
#define U_XWA   (U_D1W  + 4194304ull)       // 16,777,216 (bf16 xw, (T,4H,B))
#define U_XWB   (U_XWA  + 16777216ull)      // 16,777,216
#define U_WOUT  (U_XWB  + 16777216ull)      // 32,768,000

__device__ __forceinline__ unsigned short f2bf(float x) {
    unsigned u = __builtin_bit_cast(unsigned, x);
    return (unsigned short)((u + 0x7fffu + ((u >> 16) & 1u)) >> 16);
}
__device__ __forceinline__ float bf2f(unsigned u) {
    return __builtin_bit_cast(float, u << 16);
}

// ---------------- coherent (LLC-scope) memory helpers ----------------
__device__ __forceinline__ f4_t sc_load4(const void* p) {
    f4_t v;
    asm volatile("global_load_dwordx4 %0, %1, off sc0 sc1" : "=v"(v) : "v"(p));
    return v;                               // NOT ready until a vmcnt wait
}
__device__ __forceinline__ int sc_load1(const int* p) {
    int v;
    asm volatile("global_load_dword %0, %1, off sc0 sc1\n\ts_waitcnt vmcnt(0)"
                 : "=v"(v) : "v"(p) : "memory");
    return v;
}
__device__ __forceinline__ void sc_store_int(int* p, int v) {
    asm volatile("global_store_dword %0, %1, off sc0 sc1" :: "v"(p), "v"(v) : "memory");
}
__device__ __forceinline__ void sc_store_short(unsigned short* p, unsigned v) {
    asm volatile("global_store_short %0, %1, off sc0 sc1" :: "v"(p), "v"(v) : "memory");
}
__device__ __forceinline__ i32x2 g_load8(const void* p) {    // plain cached, no wait
    i32x2 v;
    asm volatile("global_load_dwordx2 %0, %1, off" : "=v"(v) : "v"(p));
    return v;
}
__device__ __forceinline__ void wait_vm0() {
    asm volatile("s_waitcnt vmcnt(0)" ::: "memory");
}
__device__ __forceinline__ void wait_vm8() {
    asm volatile("s_waitcnt vmcnt(8)" ::: "memory");
}

__device__ __forceinline__ void gload_lds16(const void* g, void* l) {
    __builtin_amdgcn_global_load_lds(
        (const __attribute__((address_space(1))) void*)g,
        (__attribute__((address_space(3))) void*)l, 16, 0, 0);
}

__device__ __forceinline__ float sigmoidf_(float x) { return 1.f / (1.f + expf(-x)); }

// ---------------- fp32 -> bf16 conversion ----------------
__global__ __launch_bounds__(256) void f2b_kernel(
    const float* __restrict__ in, unsigned short* __restrict__ out, int n4)
{
    const int stride = gridDim.x * 256;
    for (int i = blockIdx.x * 256 + threadIdx.x; i < n4; i += stride) {
        const float4 v = reinterpret_cast<const float4*>(in)[i];
        u16x4 o = { f2bf(v.x), f2bf(v.y), f2bf(v.z), f2bf(v.w) };
        reinterpret_cast<u16x4*>(out)[i] = o;
    }
}

// ---------------- embedding gathers (emit bf16) ----------------
__global__ __launch_bounds__(64) void embed_src_kernel(
    const int* __restrict__ toks, const float* __restrict__ emb,
    unsigned short* __restrict__ out)
{
    const int i = blockIdx.x;
    const int tok = toks[i];
    const float4 v = reinterpret_cast<const float4*>(emb + (size_t)tok * EMBD)[threadIdx.x];
    u16x4 o = { f2bf(v.x), f2bf(v.y), f2bf(v.z), f2bf(v.w) };
    reinterpret_cast<u16x4*>(out + (size_t)i * EMBD)[threadIdx.x] = o;
}

__global__ __launch_bounds__(64) void embed_dec_kernel(
    const int* __restrict__ sent, const int* __restrict__ targ,
    const float* __restrict__ emb, unsigned short* __restrict__ out)
{
    const int i = blockIdx.x;
    const int t = i >> 6, b = i & 63;
    const int tok = (t == 0) ? sent[(S_LEN - 1) * BSZ + b] : targ[(t - 1) * BSZ + b];
    const float4 v = reinterpret_cast<const float4*>(emb + (size_t)tok * EMBD)[threadIdx.x];
    u16x4 o = { f2bf(v.x), f2bf(v.y), f2bf(v.z), f2bf(v.w) };
    reinterpret_cast<u16x4*>(out + (size_t)i * EMBD)[threadIdx.x] = o;
}

// ---------------- bf16 MFMA GEMM:  C = A[M,K] * B[N,K]^T + b1 (+ b2) ----------------
// tmode 0: C fp32 row-major (M,N). tmode 1: C bf16 as (M/64, N, 64) = (T,4H,B).
__global__ __launch_bounds__(256) void gemm_bf16_kernel(
    const unsigned short* __restrict__ A, const unsigned short* __restrict__ B,
    const float* __restrict__ b1, const float* __restrict__ b2,
    void* __restrict__ Cv, int M, int N, int K, int nTN, int tmode)
{
    __shared__ __align__(16) unsigned short As[128 * 64];
    __shared__ __align__(16) unsigned short Bs[128 * 64];

    const int tid  = threadIdx.x;
    const int lane = tid & 63;
    const int wv   = tid >> 6;
    const int wm   = wv >> 1, wn = wv & 1;

    const int nwg = gridDim.x;
    const int q = nwg >> 3, r = nwg & 7;
    const int xcd = blockIdx.x & 7, io = blockIdx.x >> 3;
    const int wg = (xcd < r ? xcd * (q + 1) : r * (q + 1) + (xcd - r) * q) + io;
    const int bm = (wg / nTN) * 128;
    const int bn = (wg % nTN) * 128;

    f32x4 acc[4][4];
#pragma unroll
    for (int i = 0; i < 4; ++i)
#pragma unroll
        for (int j = 0; j < 4; ++j) acc[i][j] = (f32x4)0.f;

    const int lin_base = wv * 1024 + lane * 16;

    for (int k0 = 0; k0 < K; k0 += 64) {
        __syncthreads();
#pragma unroll
        for (int qc = 0; qc < 4; ++qc) {
            const int lin = qc * 4096 + lin_base;
            const int row = lin >> 7;
            const int c   = (lin >> 4) & 7;
            const int sc  = c ^ (row & 7);
            const size_t gofs  = (size_t)(bm + row) * K + k0 + sc * 8;
            const size_t gofsB = (size_t)(bn + row) * K + k0 + sc * 8;
            char* ldst  = (char*)As + qc * 4096 + wv * 1024;
            char* ldstB = (char*)Bs + qc * 4096 + wv * 1024;
            gload_lds16(A + gofs, ldst);
            gload_lds16(B + gofsB, ldstB);
        }
        asm volatile("s_waitcnt vmcnt(0)" ::: "memory");
        __syncthreads();
#pragma unroll
        for (int ks = 0; ks < 2; ++ks) {
            bf16x8 af[4], bfv[4];
            const int ca = ks * 4 + (lane >> 4);
#pragma unroll
            for (int f = 0; f < 4; ++f) {
                const int ra = wm * 64 + f * 16 + (lane & 15);
                af[f] = __builtin_bit_cast(bf16x8,
                    *(const s16x8*)((const char*)As + ra * 128 + ((ca ^ (ra & 7)) << 4)));
                const int rb = wn * 64 + f * 16 + (lane & 15);
                bfv[f] = __builtin_bit_cast(bf16x8,
                    *(const s16x8*)((const char*)Bs + rb * 128 + ((ca ^ (rb & 7)) << 4)));
            }
#pragma unroll
            for (int i = 0; i < 4; ++i)
#pragma unroll
                for (int j = 0; j < 4; ++j)
                    acc[i][j] = __builtin_amdgcn_mfma_f32_16x16x32_bf16(
                        af[i], bfv[j], acc[i][j], 0, 0, 0);
        }
    }

    const int col0 = bn + wn * 64 + (lane & 15);
    if (tmode == 0) {
        float* C = (float*)Cv;
        const int row0 = bm + wm * 64 + ((lane >> 4) << 2);
#pragma unroll
        for (int i = 0; i < 4; ++i) {
#pragma unroll
            for (int j = 0; j < 4; ++j) {
                const int col = col0 + j * 16;
                float bias = b1[col];
                if (b2) bias += b2[col];
#pragma unroll
                for (int rg = 0; rg < 4; ++rg)
                    C[(size_t)(row0 + i * 16 + rg) * N + col] = acc[i][j][rg] + bias;
            }
        }
    } else {
        unsigned short* C = (unsigned short*)Cv;
        const int tblk = (bm >> 6) + wm;
        const int rb = (lane >> 4) << 2;
#pragma unroll
        for (int i = 0; i < 4; ++i) {
#pragma unroll
            for (int j = 0; j < 4; ++j) {
                const int col = col0 + j * 16;
                float bias = b1[col];
                if (b2) bias += b2[col];
                u16x4 o = { f2bf(acc[i][j][0] + bias), f2bf(acc[i][j][1] + bias),
                            f2bf(acc[i][j][2] + bias), f2bf(acc[i][j][3] + bias) };
                *reinterpret_cast<u16x4*>(&C[((size_t)tblk * N + col) * 64 + rb + i * 16]) = o;
            }
        }
    }
}

// ---------------- persistent MFMA LSTM scan ----------------
// Block = (dir, bg, cb): 32 batches (bg) x 8 cells (cb). grid = ndir * 2 * (H/8) = 256.
// Sync domain = (dir, bg): blocks only poll their own domain's flags (batches independent).
// Waves (4): w = (rh<<1)|bq; bq = batch-quad-pair (16 rows), rh = cell-half.
// Lane n = gate*4+cc -> MFMA D gives 4 batches of one gate-row per lane; gates combined
// via shfl_xor(8)/(4); c-state lives in g0-lane registers. No LDS exchange passes.
// xw: bf16 (T,4H,B); hist: (T,B,1024) bf16 (h history AND y output).
template<int H_T>
__global__ __launch_bounds__(256, 1) void lstm_mfma_scan(
    const unsigned short* __restrict__ xw0, const unsigned short* __restrict__ xw1,
    const float* __restrict__ Whh0, const float* __restrict__ Whh1,
    const unsigned short* __restrict__ h0b, const float* __restrict__ c0,
    unsigned short* __restrict__ hist,
    unsigned short* __restrict__ hsb, float* __restrict__ csd,
    int T, int ndir, int rev_mask, int* bar)
{
    constexpr int KST = H_T / 32;        // MFMA k-steps
    constexpr int CH  = H_T / 8;         // 16B chunks per row
    constexpr int CPT = CH / 8;          // h-staging chunks per thread (8 enc / 16 dec)
    constexpr int NBH = CPT / 8;         // h-staging batches (1 enc / 2 dec)
    constexpr int NCB = H_T / 8;         // cell-blocks per (dir,bg)

    __shared__ __align__(16) unsigned short h_lds[32 * H_T];   // 32/64 KB
    __shared__ __align__(16) unsigned short w_lds[32 * H_T];   // 32/64 KB

    const int tid  = threadIdx.x;
    const int lane = tid & 63;
    const int w    = tid >> 6;
    const int bq   = w & 1;              // batch 16-row group
    const int rh   = w >> 1;             // cell half
    const int n    = lane & 15;          // gate*4 + cc
    const int kg   = lane >> 4;
    const int g    = n >> 2;
    const int cell = rh * 4 + (n & 3);   // 0..7

    const int nbpd = 2 * NCB;
    const int dir  = blockIdx.x / nbpd;
    const int rem  = blockIdx.x - dir * nbpd;
    const int bg   = rem / NCB;
    const int cb   = rem - bg * NCB;
    const int m0c  = cb * 8;
    const int rev  = (rev_mask >> dir) & 1;
    const unsigned short* xw = dir ? xw1 : xw0;
    const float* Whh = dir ? Whh1 : Whh0;
    const int dcol = dir * H_T;
    const int b0   = bg * 32;            // batch base

    int* myflag = bar + blockIdx.x * 32;
    const int* pollflag = bar +
        ((dir * nbpd + bg * NCB) + (tid < NCB ? tid : 0)) * 32;
    const bool polls = (tid < NCB);

    // ---- stage Whh rows (32 = 4 gates x 8 cells) into XOR-swizzled LDS, bf16 ----
    for (int idx = tid; idx < 32 * CH; idx += 256) {
        const int r_  = idx / CH, cc_ = idx - r_ * CH;
        const int gg_ = r_ >> 3, cl_ = r_ & 7;
        const float* wp = Whh + (size_t)(gg_ * H_T + m0c + cl_) * H_T + cc_ * 8;
        const float4 lo = *reinterpret_cast<const float4*>(wp);
        const float4 hi = *reinterpret_cast<const float4*>(wp + 4);
        s16x8 rr;
        rr[0] = (short)f2bf(lo.x); rr[1] = (short)f2bf(lo.y);
        rr[2] = (short)f2bf(lo.z); rr[3] = (short)f2bf(lo.w);
        rr[4] = (short)f2bf(hi.x); rr[5] = (short)f2bf(hi.y);
        rr[6] = (short)f2bf(hi.z); rr[7] = (short)f2bf(hi.w);
        *(s16x8*)((char*)w_lds + r_ * (2 * H_T) + ((cc_ ^ (r_ & 7)) << 4)) = rr;
    }

    // per g0-lane state: 4 batches (rg) of cell `cell`
    float cst[4] = {0.f, 0.f, 0.f, 0.f};
    if (g == 0 && c0) {
#pragma unroll
        for (int rg = 0; rg < 4; ++rg)
            cst[rg] = c0[(size_t)(b0 + bq * 16 + kg * 4 + rg) * HSTR + dcol + m0c + cell];
    }
    float hnv[4];

    // xw address for this lane: 4 consecutive batches = one 8B load
    const unsigned short* xbase =
        xw + ((size_t)(g * H_T + m0c + cell)) * 64 + b0 + bq * 16 + kg * 4;
    i32x2 xg;
    auto issue_xg = [&](int ttn) {
        xg = g_load8(xbase + (size_t)ttn * (4 * H_T) * 64);
    };

    // B-frag LDS row for this lane
    const int rW  = g * 8 + cell;
    const int rWx = rW & 7;
    // A-frag LDS row (batch within the 32 staged)
    const int rA  = bq * 16 + n;
    const int rAx = rA & 7;

    issue_xg(rev ? (T - 1) : 0);
    __syncthreads();                      // w_lds ready

    for (int s = 0; s < T; ++s) {
        const int tt = rev ? (T - 1 - s) : s;

        // wait for this domain's producers of step s-1 (also drains xg prefetch)
        if (s > 0) {
            int ok = polls ? 0 : 1;
            for (;;) {
                if (!ok) ok = (sc_load1(pollflag) >= s) ? 1 : 0;
                if (__syncthreads_and(ok)) break;
            }
        }

        const unsigned short* hb;
        size_t tofs;
        if (s == 0) { hb = h0b; tofs = 0; }
        else {
            const int tp = rev ? (tt + 1) : (tt - 1);
            hb = hist; tofs = (size_t)tp * (64 * 1024);
        }

        f32x4 acc = {0.f, 0.f, 0.f, 0.f};
        if (hb) {
            // ---- stage 32 x H_T h tile: sc_load4 -> XOR-swizzled LDS ----
            f4_t buf[2][8];
            auto issue = [&](int bt) {
#pragma unroll
                for (int jj = 0; jj < 8; ++jj) {
                    const int idx = (bt * 8 + jj) * 256 + tid;
                    const int rr_ = idx / CH, cc_ = idx - (idx / CH) * CH;
                    buf[bt & 1][jj] = sc_load4(
                        hb + tofs + (size_t)(b0 + rr_) * 1024 + dcol + cc_ * 8);
                }
            };
            auto writeb = [&](int bt) {
#pragma unroll
                for (int jj = 0; jj < 8; ++jj) {
                    const int idx = (bt * 8 + jj) * 256 + tid;
                    const int rr_ = idx / CH, cc_ = idx - (idx / CH) * CH;
                    *(f4_t*)((char*)h_lds + rr_ * (2 * H_T) + ((cc_ ^ (rr_ & 7)) << 4))
                        = buf[bt & 1][jj];
                }
            };
            if (NBH == 1) {
                issue(0); wait_vm0(); writeb(0);
            } else {
                issue(0); issue(1);
                wait_vm8(); writeb(0);
                wait_vm0(); writeb(1);
            }
            __syncthreads();

            // ---- MFMA: acc[rg] = pre-activation(batch=kg*4+rg, gate-row n) ----
#pragma unroll
            for (int ks = 0; ks < KST; ++ks) {
                const int ca = ks * 4 + kg;
                const bf16x8 a = __builtin_bit_cast(bf16x8,
                    *(const s16x8*)((const char*)h_lds + rA * (2 * H_T) + ((ca ^ rAx) << 4)));
                const bf16x8 bfr = __builtin_bit_cast(bf16x8,
                    *(const s16x8*)((const char*)w_lds + rW * (2 * H_T) + ((ca ^ rWx) << 4)));
                acc = __builtin_amdgcn_mfma_f32_16x16x32_bf16(a, bfr, acc, 0, 0, 0);
            }
        }

        // xw (prefetched last step) — tie to a vmcnt wait
        asm volatile("s_waitcnt vmcnt(0)" : "+v"(xg) :: "memory");
        const unsigned x0u = (unsigned)xg[0], x1u = (unsigned)xg[1];
        float xwf[4] = { bf2f(x0u & 0xffffu), bf2f(x0u >> 16),
                         bf2f(x1u & 0xffffu), bf2f(x1u >> 16) };

        // branchless gate activation: g==2 -> tanh = 2*sigmoid(2x)-1
        const bool is2 = (g == 2);
        const float kk = is2 ? 2.f : 1.f;
        const float sub = is2 ? 1.f : 0.f;
        float act[4];
#pragma unroll
        for (int rg = 0; rg < 4; ++rg) {
            const float p = acc[rg] + xwf[rg];
            act[rg] = kk * sigmoidf_(kk * p) - sub;
        }
        // combine gates onto g0 lanes: x8 = partner(g^2), x4a = sigma_f, x4b = sigma_o
        float x8[4], x4a[4], x4b[4];
#pragma unroll
        for (int rg = 0; rg < 4; ++rg) {
            x8[rg]  = __shfl_xor(act[rg], 8);
            x4a[rg] = __shfl_xor(act[rg], 4);
            x4b[rg] = __shfl_xor(x8[rg], 4);
        }
        if (g == 0) {
#pragma unroll
            for (int rg = 0; rg < 4; ++rg) {
                cst[rg] = x4a[rg] * cst[rg] + act[rg] * x8[rg];
                hnv[rg] = x4b[rg] * tanhf(cst[rg]);
                sc_store_short(hist + (size_t)tt * (64 * 1024)
                               + (size_t)(b0 + bq * 16 + kg * 4 + rg) * 1024
                               + dcol + m0c + cell, (unsigned)f2bf(hnv[rg]));
            }
        }
        wait_vm0();
        __syncthreads();                  // all waves' stores drained before flag
        if (s + 1 < T) {
            if (tid == 0) sc_store_int(myflag, s + 1);
            issue_xg(rev ? (T - 2 - s) : (s + 1));
        }
    }

    if (hsb && g == 0) {
#pragma unroll
        for (int rg = 0; rg < 4; ++rg) {
            const int b_ = b0 + bq * 16 + kg * 4 + rg;
            hsb[(size_t)b_ * 1024 + dcol + m0c + cell] = f2bf(hnv[rg]);
            csd[(size_t)b_ * HSTR + dcol + m0c + cell] = cst[rg];
        }
    }
}

// ---------------- in-place row log-softmax (float4) ----------------
__global__ __launch_bounds__(256) void logsoftmax_kernel(float* __restrict__ x, int n4)
{
    const int tid = threadIdx.x;
    float4* p = reinterpret_cast<float4*>(x + (size_t)blockIdx.x * (n4 * 4));
    float m = -3.0e38f, s = 0.f;
    for (int cc = tid; cc < n4; cc += 256) {
        const float4 v = p[cc];
        const float vv[4] = { v.x, v.y, v.z, v.w };
#pragma unroll
        for (int e = 0; e < 4; ++e) {
            const float z = vv[e];
            if (z > m) { s = s * expf(m - z) + 1.f; m = z; }
            else       { s += expf(z - m); }
        }
    }
    __shared__ float ms[256], ss[256];
    ms[tid] = m; ss[tid] = s;
    __syncthreads();
    for (int off = 128; off > 0; off >>= 1) {
        if (tid < off) {
            const float m2 = ms[tid + off], s2 = ss[tid + off];
            const float m1 = ms[tid],       s1 = ss[tid];
            const float M = fmaxf(m1, m2);
            ss[tid] = s1 * expf(m1 - M) + s2 * expf(m2 - M);
            ms[tid] = M;
        }
        __syncthreads();
    }
    const float ML = ms[0] + logf(ss[0]);
    for (int cc = tid; cc < n4; cc += 256) {
        float4 v = p[cc];
        v.x -= ML; v.y -= ML; v.z -= ML; v.w -= ML;
        p[cc] = v;
    }
}

// ---------------- host-side orchestration ----------------
extern "C" void kernel_launch(void* const* d_in, const int* in_sizes, int n_in,
                              void* d_out, int out_size, void* d_ws, size_t ws_size,
                              hipStream_t stream)
{
    const int*   sent  = (const int*)d_in[0];
    const int*   targ  = (const int*)d_in[1];
    const float* emb   = (const float*)d_in[2];
    const float* e0Wih = (const float*)d_in[3];
    const float* e0Whh = (const float*)d_in[4];
    const float* e0bih = (const float*)d_in[5];
    const float* e0bhh = (const float*)d_in[6];
    const float* e1Wih = (const float*)d_in[7];
    const float* e1Whh = (const float*)d_in[8];
    const float* e1bih = (const float*)d_in[9];
    const float* e1bhh = (const float*)d_in[10];
    const float* d0Wih = (const float*)d_in[11];
    const float* d0Whh = (const float*)d_in[12];
    const float* d0bih = (const float*)d_in[13];
    const float* d0bhh = (const float*)d_in[14];
    const float* d1Wih = (const float*)d_in[15];
    const float* d1Whh = (const float*)d_in[16];
    const float* d1bih = (const float*)d_in[17];
    const float* d1bhh = (const float*)d_in[18];
    const float* Wout  = (const float*)d_in[19];
    const float* bout  = (const float*)d_in[20];

    float* ws  = (float*)d_ws;
    float* cs  = ws + WS_CS;
    int*   bar = (int*)(ws + WS_BAR);
    unsigned short* ub    = (unsigned short*)(ws + WS_BF);
    unsigned short* x0b   = ub + U_X0B;
    unsigned short* h_e0  = ub + U_HE0;
    unsigned short* h_e1  = ub + U_HE1;
    unsigned short* h_d0  = ub + U_HD0;
    unsigned short* h_d1  = ub + U_HD1;
    unsigned short* hsb   = ub + U_HSB;
    unsigned short* e0Wb  = ub + U_E0W;
    unsigned short* e1Wb  = ub + U_E1W;
    unsigned short* d0Wb  = ub + U_D0W;
    unsigned short* d1Wb  = ub + U_D1W;
    unsigned short* xwA   = ub + U_XWA;
    unsigned short* xwB   = ub + U_XWB;
    unsigned short* Woutb = ub + U_WOUT;
    float* out = (float*)d_out;

    hipMemsetAsync(bar, 0, 4 * 8192 * sizeof(int), stream);

    // ---- weight conversions (fp32 -> bf16) ----
    f2b_kernel<<<256, 256, 0, stream>>>(e0Wih, e0Wb, 1048576 / 4);
    f2b_kernel<<<512, 256, 0, stream>>>(e1Wih, e1Wb, 4194304 / 4);
    f2b_kernel<<<256, 256, 0, stream>>>(d0Wih, d0Wb, 1048576 / 4);
    f2b_kernel<<<512, 256, 0, stream>>>(d1Wih, d1Wb, 4194304 / 4);
    f2b_kernel<<<2048, 256, 0, stream>>>(Wout, Woutb, (VOC_ * DHID_) / 4);

    // ---- encoder layer 0 ----
    embed_src_kernel<<<S_LEN * BSZ, 64, 0, stream>>>(sent, emb, x0b);
    gemm_bf16_kernel<<<64 * 16, 256, 0, stream>>>(x0b, e0Wb, e0bih, e0bhh, xwA,
                                                  S_LEN * BSZ, 2048, EMBD, 16, 1);
    gemm_bf16_kernel<<<64 * 16, 256, 0, stream>>>(x0b, e0Wb + 2048ull * 256,
                                                  e0bih + 2048, e0bhh + 2048, xwB,
                                                  S_LEN * BSZ, 2048, EMBD, 16, 1);
    lstm_mfma_scan<512><<<256, 256, 0, stream>>>(xwA, xwB, e0Whh, e0Whh + 2048ull * 512,
                                                 nullptr, nullptr, h_e0,
                                                 hsb, cs, S_LEN, 2, 2, bar);
    // ---- encoder layer 1 (final states only) ----
    gemm_bf16_kernel<<<64 * 16, 256, 0, stream>>>(h_e0, e1Wb, e1bih, e1bhh, xwA,
                                                  S_LEN * BSZ, 2048, 2 * HID_, 16, 1);
    gemm_bf16_kernel<<<64 * 16, 256, 0, stream>>>(h_e0, e1Wb + 2048ull * 1024,
                                                  e1bih + 2048, e1bhh + 2048, xwB,
                                                  S_LEN * BSZ, 2048, 2 * HID_, 16, 1);
    lstm_mfma_scan<512><<<256, 256, 0, stream>>>(xwA, xwB, e1Whh, e1Whh + 2048ull * 512,
                                                 nullptr, nullptr, h_e1,
                                                 hsb + 65536, cs + 65536,
                                                 S_LEN, 2, 2, bar + 8192);
    // ---- decoder layer 0 ----
    embed_dec_kernel<<<T_LEN * BSZ, 64, 0, stream>>>(sent, targ, emb, x0b);
    gemm_bf16_kernel<<<32 * 32, 256, 0, stream>>>(x0b, d0Wb, d0bih, d0bhh, xwA,
                                                  T_LEN * BSZ, 4 * DHID_, EMBD, 32, 1);
    lstm_mfma_scan<1024><<<256, 256, 0, stream>>>(xwA, nullptr, d0Whh, nullptr,
                                                  hsb, cs, h_d0,
                                                  nullptr, nullptr, T_LEN, 1, 0,
                                                  bar + 2 * 8192);
    // ---- decoder layer 1 ----
    gemm_bf16_kernel<<<32 * 32, 256, 0, stream>>>(h_d0, d1Wb, d1bih, d1bhh, xwB,
                                                  T_LEN * BSZ, 4 * DHID_, DHID_, 32, 1);
    lstm_mfma_scan<1024><<<256, 256, 0, stream>>>(xwB, nullptr, d1Whh, nullptr,
                                                  hsb + 65536, cs + 65536, h_d1,
                                                  nullptr, nullptr, T_LEN, 1, 0,
                                                  bar + 3 * 8192);
    // ---- vocab projection + log-softmax ----
    gemm_bf16_kernel<<<32 * 250, 256, 0, stream>>>(h_d1, Woutb, bout, nullptr, out,
                                                   T_LEN * BSZ, VOC_, DHID_, 250, 0);
    logsoftmax_kernel<<<T_LEN * BSZ, 256, 0, stream>>>(out, VOC_ / 4);
}